// Round 1
// 1831.323 us; speedup vs baseline: 1.0382x; 1.0382x over previous
//
#include <hip/hip_runtime.h>
#include <stdint.h>

// CfC RNN: B=256, T=1024, I=64, U=256, O=64, BB=128. All I/O float32.
//
// MFMA version: 16 batch rows per WG (M=16 fragments), 16 WGs x 512 thr
// (8 waves, 2 waves/SIMD -> 256-VGPR budget). Per step:
//   bb:  Z[16x320] @ W_bb[320x128]  -> 10 mfma_16x16x32_f16 per wave (1 n-tile)
//   ff:  G[16x128] @ [Wff1|Wff2|Wta+Wtb][128x768] -> 24 mfma per wave (6 tiles)
// Weights live in VGPRs as f16 pairs; activations are staged through LDS in a
// SELF-CONSISTENT A-fragment layout: both A (z,g) and B (weights) use
// k = c*32 + (lane>>4)*8 + elem, so any HW k-permutation cancels. Only the
// HW-verified D layout (col=lane&15, row=(lane>>4)*4+reg) is relied upon.
// ts=1.0 folds W_ta+W_tb into one matmul. Hbuf layout (packed f16 unit-pairs
// [row][t][u/2]) matches the old kernel, so ro_kernel is unchanged.
#define B_ 256
#define T_ 1024
#define I_ 64
#define U_ 256
#define O_ 64
#define BB_ 128

typedef unsigned int u32;
typedef unsigned short u16;
typedef _Float16 half2_t __attribute__((ext_vector_type(2)));
typedef _Float16 f16x8 __attribute__((ext_vector_type(8)));
typedef float f32x4 __attribute__((ext_vector_type(4)));

#if defined(__has_builtin)
#if __has_builtin(__builtin_amdgcn_fdot2)
#define USE_DOT2 1
#else
#define USE_DOT2 0
#endif
#else
#define USE_DOT2 0
#endif

static __device__ __forceinline__ u32 packpair(float a, float b) {
  half2_t h; h.x = (_Float16)a; h.y = (_Float16)b;
  return __builtin_bit_cast(u32, h);
}
static __device__ __forceinline__ float unpack_lo(u32 u) {
  half2_t h = __builtin_bit_cast(half2_t, u); return (float)h.x;
}
static __device__ __forceinline__ float unpack_hi(u32 u) {
  half2_t h = __builtin_bit_cast(half2_t, u); return (float)h.y;
}
static __device__ __forceinline__ float dot2acc(u32 w, u32 z, float acc) {
#if USE_DOT2
  return __builtin_amdgcn_fdot2(__builtin_bit_cast(half2_t, w),
                                __builtin_bit_cast(half2_t, z), acc, false);
#else
  half2_t hw = __builtin_bit_cast(half2_t, w);
  half2_t hz = __builtin_bit_cast(half2_t, z);
  acc += (float)hw.x * (float)hz.x;
  acc += (float)hw.y * (float)hz.y;
  return acc;
#endif
}

// DPP cross-lane moves (VALU pipe; no LDS). Palindromic controls only.
template <int CTRL>
static __device__ __forceinline__ float dpp_mov_f(float v) {
  return __builtin_bit_cast(float, __builtin_amdgcn_update_dpp(
      0, __builtin_bit_cast(int, v), CTRL, 0xF, 0xF, true));
}
#define DPP_XOR1 0xB1
#define DPP_XOR2 0x4E
#define DPP_HMIR 0x141
#define DPP_MIRR 0x140

static __device__ __forceinline__ float fast_tanh(float x) {
  return 1.0f - 2.0f / (1.0f + __expf(2.0f * x));
}
static __device__ __forceinline__ float fast_sigmoid(float x) {
  return 1.0f / (1.0f + __expf(-x));
}

static __device__ __forceinline__ float rcpf(float x) {
#if defined(__has_builtin) && __has_builtin(__builtin_amdgcn_rcpf)
  return __builtin_amdgcn_rcpf(x);
#else
  return 1.0f / x;
#endif
}
static __device__ __forceinline__ float exp2fast(float x) {
#if defined(__has_builtin) && __has_builtin(__builtin_amdgcn_exp2f)
  return __builtin_amdgcn_exp2f(x);
#else
  return exp2f(x);
#endif
}

static __device__ __forceinline__ f32x4 mfma16(uint4 a, uint4 b, f32x4 c) {
  return __builtin_amdgcn_mfma_f32_16x16x32_f16(
      __builtin_bit_cast(f16x8, a), __builtin_bit_cast(f16x8, b), c, 0, 0, 0);
}

#define LOG2E 1.44269504f

// ============================ MFMA main kernel ============================
__global__ __launch_bounds__(512, 2)
void cfc_mfma(const float* __restrict__ x,
              const float* __restrict__ W_bb, const float* __restrict__ b_bb,
              const float* __restrict__ W_ff1, const float* __restrict__ b_ff1,
              const float* __restrict__ W_ff2, const float* __restrict__ b_ff2,
              const float* __restrict__ W_ta,  const float* __restrict__ b_ta,
              const float* __restrict__ W_tb,  const float* __restrict__ b_tb,
              float* __restrict__ out, u32* __restrict__ Hbuf)
{
  // z A-frags: [10 chunks][64 lanes][4 u32]  (k = c*32 + (lane>>4)*8 + elem)
  //   chunks 0..1 = x_t (k=0..63), chunks 2..9 = h (k=64..319)
  __shared__ __align__(16) u32 s_z[2560];
  // g A-frags: [4 chunks][64 lanes][4 u32]
  __shared__ __align__(16) u32 s_g[1024];

  const int tid = threadIdx.x;
  const int l   = tid & 63;        // lane
  const int w   = tid >> 6;        // wave 0..7
  const int c16 = l & 15;          // n / m within fragment
  const int q4  = l >> 4;          // k-group (A/B) or row-group (D)
  const int odd = l & 1;
  const int row0 = blockIdx.x * 16;

  // ---- weights -> VGPRs as B-fragments (f16 pairs along k) ----
  // bb: wave w owns n-tile w (cols w*16..w*16+15), 10 k-chunks.
  uint4 wbb[10];
  {
    const int colb = w * 16 + c16;
#pragma unroll
    for (int c = 0; c < 10; ++c) {
      u32 qv[4];
#pragma unroll
      for (int q = 0; q < 4; ++q) {
        const int k0 = c * 32 + q4 * 8 + 2 * q;
        qv[q] = packpair(W_bb[(size_t)k0 * BB_ + colb],
                         W_bb[(size_t)(k0 + 1) * BB_ + colb]);
      }
      wbb[c] = make_uint4(qv[0], qv[1], qv[2], qv[3]);
    }
  }
  // ff: wave w owns units u = w*32 .. w*32+31 (2 tiles) for each of 3 mats:
  //   mat0 = W_ff1, mat1 = W_ff2, mat2 = W_ta + W_tb (ts = 1.0 fold).
  uint4 wff[3][2][4];
#pragma unroll
  for (int ut = 0; ut < 2; ++ut) {
    const int u = w * 32 + ut * 16 + c16;
#pragma unroll
    for (int c = 0; c < 4; ++c) {
      u32 qa[4], qb[4], qc[4];
#pragma unroll
      for (int q = 0; q < 4; ++q) {
        const int k0 = c * 32 + q4 * 8 + 2 * q;
        const size_t i0 = (size_t)k0 * U_ + u, i1 = i0 + U_;
        qa[q] = packpair(W_ff1[i0], W_ff1[i1]);
        qb[q] = packpair(W_ff2[i0], W_ff2[i1]);
        qc[q] = packpair(W_ta[i0] + W_tb[i0], W_ta[i1] + W_tb[i1]);
      }
      wff[0][ut][c] = make_uint4(qa[0], qa[1], qa[2], qa[3]);
      wff[1][ut][c] = make_uint4(qb[0], qb[1], qb[2], qb[3]);
      wff[2][ut][c] = make_uint4(qc[0], qc[1], qc[2], qc[3]);
    }
  }

  // ---- biases, pre-scaled for exp2-based tanh/sigmoid ----
  // g  = 1.7159*tanh(0.666*(a+b))  -> r = rcp(exp2(fma(a,1.332*log2e,bgs))+1)
  //                                    g = fma(r,-3.4318,1.7159)
  // f  = tanh(a+b)                 -> f = fma(r,-2,1), arg scale 2*log2e
  // ti = sigmoid(a+bt)             -> ti = rcp(exp2(fma(a,-log2e,btn))+1)
  const float bgs = b_bb[w * 16 + c16] * (1.332f * LOG2E);
  float b1s[2], b2s[2], btn[2];
#pragma unroll
  for (int ut = 0; ut < 2; ++ut) {
    const int u = w * 32 + ut * 16 + c16;
    b1s[ut] = b_ff1[u] * (2.0f * LOG2E);
    b2s[ut] = b_ff2[u] * (2.0f * LOG2E);
    btn[ut] = -(b_ta[u] + b_tb[u]) * LOG2E;
  }

  // ---- x staging map: thread (m = tid>>5, p = tid&31) owns x pair k=2p ----
  const int mx = tid >> 5, px = tid & 31;
  const float* xptr = x + (size_t)(row0 + mx) * T_ * I_ + 2 * px;
  const int zxw = ((px >> 4) * 64 + mx + 16 * ((px >> 2) & 3)) * 4 + (px & 3);

  // ---- g-staging / h-staging write addresses (D-frag -> A-frag repack) ----
  // D: value at (row m = q4*4+r, col n). Pair cols (n, n^1) via DPP xor1.
  // Even lane writes rows r=0,1; odd lane writes rows r=2,3 (same pair word).
  const int rbase = odd ? 2 : 0;
  const int m0 = q4 * 4 + rbase, m1 = m0 + 1;
  const int pg = w * 8 + (c16 >> 1);  // g pair index 0..63
  const int gw0 = ((pg >> 4) * 64 + 16 * ((pg >> 2) & 3)) * 4 + (pg & 3)
                  + 16 * q4 + (odd ? 8 : 0);
  int zw_[2]; size_t hb0_[2], hb1_[2];
#pragma unroll
  for (int ut = 0; ut < 2; ++ut) {
    const int pu = w * 16 + ut * 8 + (c16 >> 1);  // h pair index 0..127
    zw_[ut] = ((2 + (pu >> 4)) * 64 + 16 * ((pu >> 2) & 3)) * 4 + (pu & 3)
              + 16 * q4 + (odd ? 8 : 0);
    hb0_[ut] = (size_t)(row0 + m0) * T_ * 128 + pu;
    hb1_[ut] = (size_t)(row0 + m1) * T_ * 128 + pu;
  }

  // ---- prologue: h=0, stage x_0 ----
  reinterpret_cast<uint4*>(s_z)[128 + tid] = make_uint4(0u, 0u, 0u, 0u);
  {
    float2 xv = *(const float2*)xptr;
    s_z[zxw] = packpair(xv.x, xv.y);
  }
  __syncthreads();

  const uint4* z4 = (const uint4*)s_z;
  const uint4* g4 = (const uint4*)s_g;

  for (int t = 0; t < T_; ++t) {
    // prefetch x_{t+1}
    float2 xv;
    const bool ldx = (t + 1 < T_);
    if (ldx) xv = *(const float2*)(xptr + (size_t)(t + 1) * I_);

    // ================= backbone: G = Z @ W_bb =================
    f32x4 aA = {0.f, 0.f, 0.f, 0.f}, aB = {0.f, 0.f, 0.f, 0.f};
#pragma unroll
    for (int c = 0; c < 10; c += 2) {
      aA = mfma16(z4[c * 64 + l],       wbb[c],     aA);
      aB = mfma16(z4[(c + 1) * 64 + l], wbb[c + 1], aB);
    }
    const f32x4 ab = aA + aB;

    // g = lecun_tanh(acc + b_bb); pack col-pairs; stage as ff A-frags
    u32 gq[4];
#pragma unroll
    for (int r = 0; r < 4; ++r) {
      const float a  = __builtin_fmaf(ab[r], 1.332f * LOG2E, bgs);
      const float rr = rcpf(exp2fast(a) + 1.0f);
      const float g  = __builtin_fmaf(rr, -3.4318f, 1.7159f);
      const float gp = dpp_mov_f<DPP_XOR1>(g);
      gq[r] = odd ? packpair(gp, g) : packpair(g, gp);
    }
    s_g[gw0]     = odd ? gq[2] : gq[0];
    s_g[gw0 + 4] = odd ? gq[3] : gq[1];
    __syncthreads();

    // ================= ff: [f1|f2|t] = G @ Wcat =================
    f32x4 af[3][2];
#pragma unroll
    for (int mt = 0; mt < 3; ++mt)
#pragma unroll
      for (int ut = 0; ut < 2; ++ut)
        af[mt][ut] = (f32x4){0.f, 0.f, 0.f, 0.f};
#pragma unroll
    for (int c = 0; c < 4; ++c) {
      const uint4 ga = g4[c * 64 + l];
#pragma unroll
      for (int mt = 0; mt < 3; ++mt)
#pragma unroll
        for (int ut = 0; ut < 2; ++ut)
          af[mt][ut] = mfma16(ga, wff[mt][ut][c], af[mt][ut]);
    }

    // ================= combine -> h; stage for next z; write Hbuf ========
#pragma unroll
    for (int ut = 0; ut < 2; ++ut) {
      u32 hq[4];
#pragma unroll
      for (int r = 0; r < 4; ++r) {
        const float a1 = __builtin_fmaf(af[0][ut][r], 2.0f * LOG2E, b1s[ut]);
        const float f1 = __builtin_fmaf(rcpf(exp2fast(a1) + 1.0f), -2.0f, 1.0f);
        const float a2 = __builtin_fmaf(af[1][ut][r], 2.0f * LOG2E, b2s[ut]);
        const float f2 = __builtin_fmaf(rcpf(exp2fast(a2) + 1.0f), -2.0f, 1.0f);
        const float at = __builtin_fmaf(af[2][ut][r], -LOG2E, btn[ut]);
        const float ti = rcpf(exp2fast(at) + 1.0f);
        const float h  = __builtin_fmaf(ti, f2 - f1, f1);
        const float hp = dpp_mov_f<DPP_XOR1>(h);
        hq[r] = odd ? packpair(hp, h) : packpair(h, hp);
      }
      const u32 s0 = odd ? hq[2] : hq[0];
      const u32 s1 = odd ? hq[3] : hq[1];
      s_z[zw_[ut]]     = s0;
      s_z[zw_[ut] + 4] = s1;
      Hbuf[hb0_[ut] + (size_t)t * 128] = s0;
      Hbuf[hb1_[ut] + (size_t)t * 128] = s1;
    }
    if (ldx) s_z[zxw] = packpair(xv.x, xv.y);
    __syncthreads();
  }

  // ---- h_last tail: unpack h region of s_z -> out + B*T*O as float2 ----
  {
    const uint4 hv = reinterpret_cast<const uint4*>(s_z)[128 + tid];
    float2* tail = (float2*)(out + (size_t)B_ * T_ * O_);
#pragma unroll
    for (int i = 0; i < 4; ++i) {
      const int vh   = tid * 4 + i;          // word index within h region
      const int ch   = vh >> 8;              // chunk-2
      const int lane = (vh >> 2) & 63;
      const int slot = vh & 3;
      const int m    = lane & 15;
      const int bq   = lane >> 4;
      const int pu   = ch * 16 + bq * 4 + slot;
      const u32 hp   = (i == 0) ? hv.x : (i == 1) ? hv.y : (i == 2) ? hv.z : hv.w;
      float2 hf; hf.x = unpack_lo(hp); hf.y = unpack_hi(hp);
      tail[(size_t)(row0 + m) * 128 + pu] = hf;
    }
  }
}

// ================= fallback (no workspace): previous dot2 kernel ==========
template <bool DEFER>
__global__ __launch_bounds__(1024)
void cfc_kernel(const float* __restrict__ x,
                const float* __restrict__ W_bb, const float* __restrict__ b_bb,
                const float* __restrict__ W_ff1, const float* __restrict__ b_ff1,
                const float* __restrict__ W_ff2, const float* __restrict__ b_ff2,
                const float* __restrict__ W_ta,  const float* __restrict__ b_ta,
                const float* __restrict__ W_tb,  const float* __restrict__ b_tb,
                const float* __restrict__ W_fc,  const float* __restrict__ b_fc,
                float* __restrict__ out, u32* __restrict__ Hbuf)
{
  __shared__ __align__(16) u32 s_z2[160];
  __shared__ __align__(16) u32 s_g2[64];
  u16* s_gh = (u16*)s_g2;

  const int tid = threadIdx.x;
  const int r   = blockIdx.x;

  const int ca  = tid >> 3;
  const int kga = tid & 7;
  const int jb = tid >> 2;
  const int kq = tid & 3;
  const int ro = tid >> 4;
  const int rk = tid & 15;

  u32 wbb[20];
#pragma unroll
  for (int j = 0; j < 5; ++j)
#pragma unroll
    for (int q = 0; q < 4; ++q) {
      int p = 4 * (kga + 8 * j) + q;
      wbb[4 * j + q] = packpair(W_bb[(2 * p) * BB_ + ca],
                                W_bb[(2 * p + 1) * BB_ + ca]);
    }
  u32 wf1[16], wf2[16], wta[16], wtb[16];
#pragma unroll
  for (int j = 0; j < 4; ++j)
#pragma unroll
    for (int q = 0; q < 4; ++q) {
      int p = 4 * (kq + 4 * j) + q;
      int k0 = 2 * p, k1 = 2 * p + 1;
      wf1[4 * j + q] = packpair(W_ff1[k0 * U_ + jb], W_ff1[k1 * U_ + jb]);
      wf2[4 * j + q] = packpair(W_ff2[k0 * U_ + jb], W_ff2[k1 * U_ + jb]);
      wta[4 * j + q] = packpair(W_ta [k0 * U_ + jb], W_ta [k1 * U_ + jb]);
      wtb[4 * j + q] = packpair(W_tb [k0 * U_ + jb], W_tb [k1 * U_ + jb]);
    }
  u32 wfc[8];
  float bfo = 0.f;
  if (!DEFER) {
#pragma unroll
    for (int j = 0; j < 2; ++j)
#pragma unroll
      for (int q = 0; q < 4; ++q) {
        int p = 4 * (rk + 16 * j) + q;
        wfc[4 * j + q] = packpair(W_fc[(2 * p) * O_ + ro],
                                  W_fc[(2 * p + 1) * O_ + ro]);
      }
    bfo = b_fc[ro];
  }
  const float bbbc = b_bb[ca];
  const float b1 = b_ff1[jb], b2 = b_ff2[jb];
  const float bta = b_ta[jb], btb = b_tb[jb];

  const float* xrow = x + (size_t)r * T_ * I_;
  const size_t out_row = (size_t)r * T_ * O_;
  u32* __restrict__ hrow = DEFER ? (Hbuf + (size_t)r * T_ * (U_ / 2)) : nullptr;

  if (tid < 160) s_z2[tid] = 0u;
  __syncthreads();
  if (tid < 32) {
    float2 xv = ((const float2*)xrow)[tid];
    s_z2[tid] = packpair(xv.x, xv.y);
  }
  __syncthreads();

  for (int t = 0; t < T_; ++t) {
    float2 xv;
    const bool ldx = (tid < 32) && (t + 1 < T_);
    if (ldx) xv = ((const float2*)(xrow + (size_t)(t + 1) * I_))[tid];

    float bacc = 0.f;
#pragma unroll
    for (int j = 0; j < 5; ++j) {
      uint4 zz = *reinterpret_cast<const uint4*>(s_z2 + 4 * (kga + 8 * j));
      bacc = dot2acc(wbb[4 * j + 0], zz.x, bacc);
      bacc = dot2acc(wbb[4 * j + 1], zz.y, bacc);
      bacc = dot2acc(wbb[4 * j + 2], zz.z, bacc);
      bacc = dot2acc(wbb[4 * j + 3], zz.w, bacc);
    }
    bacc += dpp_mov_f<DPP_XOR1>(bacc);
    bacc += dpp_mov_f<DPP_XOR2>(bacc);
    bacc += dpp_mov_f<DPP_HMIR>(bacc);
    float g = 1.7159f * fast_tanh(0.666f * (bacc + bbbc));

    float racc = 0.f;
    if (!DEFER) {
#pragma unroll
      for (int j = 0; j < 2; ++j) {
        uint4 hh = *reinterpret_cast<const uint4*>(s_z2 + 32 + 4 * (rk + 16 * j));
        racc = dot2acc(wfc[4 * j + 0], hh.x, racc);
        racc = dot2acc(wfc[4 * j + 1], hh.y, racc);
        racc = dot2acc(wfc[4 * j + 2], hh.z, racc);
        racc = dot2acc(wfc[4 * j + 3], hh.w, racc);
      }
      racc += dpp_mov_f<DPP_XOR1>(racc);
      racc += dpp_mov_f<DPP_XOR2>(racc);
      racc += dpp_mov_f<DPP_HMIR>(racc);
      racc += dpp_mov_f<DPP_MIRR>(racc);
    }
    if ((tid & 7) == 0)
      s_gh[ca] = __builtin_bit_cast(u16, (_Float16)g);
    if (!DEFER && t > 0 && rk == 0)
      out[out_row + (size_t)(t - 1) * O_ + ro] = racc + bfo;
    __syncthreads();

    float a1 = 0.f, a2 = 0.f, a3 = 0.f, a4 = 0.f;
#pragma unroll
    for (int j = 0; j < 4; ++j) {
      uint4 gg = *reinterpret_cast<const uint4*>(s_g2 + 4 * (kq + 4 * j));
      a1 = dot2acc(wf1[4 * j + 0], gg.x, a1);
      a1 = dot2acc(wf1[4 * j + 1], gg.y, a1);
      a1 = dot2acc(wf1[4 * j + 2], gg.z, a1);
      a1 = dot2acc(wf1[4 * j + 3], gg.w, a1);
      a2 = dot2acc(wf2[4 * j + 0], gg.x, a2);
      a2 = dot2acc(wf2[4 * j + 1], gg.y, a2);
      a2 = dot2acc(wf2[4 * j + 2], gg.z, a2);
      a2 = dot2acc(wf2[4 * j + 3], gg.w, a2);
      a3 = dot2acc(wta[4 * j + 0], gg.x, a3);
      a3 = dot2acc(wta[4 * j + 1], gg.y, a3);
      a3 = dot2acc(wta[4 * j + 2], gg.z, a3);
      a3 = dot2acc(wta[4 * j + 3], gg.w, a3);
      a4 = dot2acc(wtb[4 * j + 0], gg.x, a4);
      a4 = dot2acc(wtb[4 * j + 1], gg.y, a4);
      a4 = dot2acc(wtb[4 * j + 2], gg.z, a4);
      a4 = dot2acc(wtb[4 * j + 3], gg.w, a4);
    }
    a1 += dpp_mov_f<DPP_XOR1>(a1); a1 += dpp_mov_f<DPP_XOR2>(a1);
    a2 += dpp_mov_f<DPP_XOR1>(a2); a2 += dpp_mov_f<DPP_XOR2>(a2);
    a3 += dpp_mov_f<DPP_XOR1>(a3); a3 += dpp_mov_f<DPP_XOR2>(a3);
    a4 += dpp_mov_f<DPP_XOR1>(a4); a4 += dpp_mov_f<DPP_XOR2>(a4);
    float f1 = fast_tanh(a1 + b1);
    float f2 = fast_tanh(a2 + b2);
    float ti = fast_sigmoid(a3 + bta + a4 + btb);
    float h  = f1 + ti * (f2 - f1);
    float hq = dpp_mov_f<DPP_HMIR>(h);

    if ((tid & 7) == 0) {
      u32 pr = packpair(h, hq);
      int m = tid >> 3;
      s_z2[32 + m] = pr;
      if (DEFER) hrow[(size_t)t * (U_ / 2) + m] = pr;
    }
    if (ldx) s_z2[tid] = packpair(xv.x, xv.y);
    __syncthreads();
  }

  if (!DEFER) {
    float racc = 0.f;
#pragma unroll
    for (int j = 0; j < 2; ++j) {
      uint4 hh = *reinterpret_cast<const uint4*>(s_z2 + 32 + 4 * (rk + 16 * j));
      racc = dot2acc(wfc[4 * j + 0], hh.x, racc);
      racc = dot2acc(wfc[4 * j + 1], hh.y, racc);
      racc = dot2acc(wfc[4 * j + 2], hh.z, racc);
      racc = dot2acc(wfc[4 * j + 3], hh.w, racc);
    }
    racc += dpp_mov_f<DPP_XOR1>(racc);
    racc += dpp_mov_f<DPP_XOR2>(racc);
    racc += dpp_mov_f<DPP_HMIR>(racc);
    racc += dpp_mov_f<DPP_MIRR>(racc);
    if (rk == 0)
      out[out_row + (size_t)(T_ - 1) * O_ + ro] = racc + bfo;
  }

  if (tid < 128) {
    u32 hp = s_z2[32 + tid];
    float2 hv; hv.x = unpack_lo(hp); hv.y = unpack_hi(hp);
    ((float2*)(out + (size_t)B_ * T_ * O_))[r * 128 + tid] = hv;
  }
}

// Deferred readout: out[r,t,:] = H[r,t,:] @ W_fc + b_fc. (unchanged)
__global__ __launch_bounds__(512)
void ro_kernel(const u32* __restrict__ Hbuf,
               const float* __restrict__ W_fc, const float* __restrict__ b_fc,
               float* __restrict__ out)
{
  __shared__ __align__(16) u32 s_h[8 * 128];
  const int tid = threadIdx.x;
  const int o   = tid & 63;
  const int w   = tid >> 6;
  const int r   = blockIdx.x;

  u32 wfc[128];
#pragma unroll
  for (int p = 0; p < 128; ++p)
    wfc[p] = packpair(W_fc[(2 * p) * O_ + o], W_fc[(2 * p + 1) * O_ + o]);
  const float bo = b_fc[o];

  const u32* hrow = Hbuf + (size_t)r * T_ * 128;
  const size_t out_row = (size_t)r * T_ * O_;

  for (int c = 0; c < T_ / 8; ++c) {
    *(uint2*)(s_h + 2 * tid) =
        *(const uint2*)(hrow + (size_t)c * 1024 + 2 * tid);
    __syncthreads();
    float acc = bo;
    const uint4* h4 = reinterpret_cast<const uint4*>(s_h + w * 128);
#pragma unroll
    for (int i = 0; i < 32; ++i) {
      uint4 hh = h4[i];
      acc = dot2acc(wfc[4 * i + 0], hh.x, acc);
      acc = dot2acc(wfc[4 * i + 1], hh.y, acc);
      acc = dot2acc(wfc[4 * i + 2], hh.z, acc);
      acc = dot2acc(wfc[4 * i + 3], hh.w, acc);
    }
    out[out_row + (size_t)(8 * c + w) * O_ + o] = acc;
    __syncthreads();
  }
}

extern "C" void kernel_launch(void* const* d_in, const int* in_sizes, int n_in,
                              void* d_out, int out_size, void* d_ws, size_t ws_size,
                              hipStream_t stream) {
  const float* x     = (const float*)d_in[0];
  const float* W_bb  = (const float*)d_in[1];
  const float* b_bb  = (const float*)d_in[2];
  const float* W_ff1 = (const float*)d_in[3];
  const float* b_ff1 = (const float*)d_in[4];
  const float* W_ff2 = (const float*)d_in[5];
  const float* b_ff2 = (const float*)d_in[6];
  const float* W_ta  = (const float*)d_in[7];
  const float* b_ta  = (const float*)d_in[8];
  const float* W_tb  = (const float*)d_in[9];
  const float* b_tb  = (const float*)d_in[10];
  const float* W_fc  = (const float*)d_in[11];
  const float* b_fc  = (const float*)d_in[12];
  float* out = (float*)d_out;

  const size_t h_bytes = (size_t)B_ * T_ * (U_ / 2) * sizeof(u32);  // 128 MiB
  if (ws_size >= h_bytes) {
    u32* Hbuf = (u32*)d_ws;
    cfc_mfma<<<dim3(B_ / 16), dim3(512), 0, stream>>>(
        x, W_bb, b_bb, W_ff1, b_ff1, W_ff2, b_ff2,
        W_ta, b_ta, W_tb, b_tb, out, Hbuf);
    ro_kernel<<<dim3(B_), dim3(512), 0, stream>>>(Hbuf, W_fc, b_fc, out);
  } else {
    cfc_kernel<false><<<dim3(B_), dim3(1024), 0, stream>>>(
        x, W_bb, b_bb, W_ff1, b_ff1, W_ff2, b_ff2,
        W_ta, b_ta, W_tb, b_tb, W_fc, b_fc, out, nullptr);
  }
}